// Round 11
// baseline (2047.944 us; speedup 1.0000x reference)
//
#include <hip/hip_runtime.h>
#include <hip/hip_bf16.h>

typedef __bf16 bf16x8 __attribute__((ext_vector_type(8)));
typedef float f32x4 __attribute__((ext_vector_type(4)));
typedef unsigned short ushort8 __attribute__((ext_vector_type(8)));
typedef float float4v __attribute__((ext_vector_type(4)));
typedef unsigned int uint4v __attribute__((ext_vector_type(4)));
typedef unsigned long long u64;
typedef unsigned int u32;

#define DEVI __device__ __forceinline__

// ---- sizes (compile-time) ----
#define NSEQ 256      // A_*BS
#define TT 256        // T
#define VV 128        // V
#define EE 512        // E
#define HH 512        // H
#define NA 64
#define MROWS 65536   // NSEQ*T
#define G3 1536       // 3*H

DEVI unsigned short f2bf(float f) {
  union { float f; unsigned u; } v; v.f = f;
  unsigned r = v.u + 0x7fffu + ((v.u >> 16) & 1u);
  return (unsigned short)(r >> 16);
}
DEVI float bf2f(unsigned short s) {
  union { unsigned u; float f; } v; v.u = ((unsigned)s) << 16;
  return v.f;
}
DEVI bf16x8 ld_bf8_g(const unsigned short* p) {
  ushort8 v = *(const ushort8*)p;
  return __builtin_bit_cast(bf16x8, v);
}
DEVI bf16x8 ld_bf8_b(const char* base, unsigned byte) {
  ushort8 v = *(const ushort8*)(base + byte);
  return __builtin_bit_cast(bf16x8, v);
}
DEVI void gload_lds16(const void* g, unsigned short* lds_base, unsigned lds_byte_off) {
  __builtin_amdgcn_global_load_lds(
      (const __attribute__((address_space(1))) unsigned int*)g,
      (__attribute__((address_space(3))) unsigned int*)(void*)((char*)lds_base + lds_byte_off),
      16, 0, 0);
}
// LLC-coherent 32B load (bypass L1+L2). Issue only; caller waits vmcnt.
DEVI void ld32_sc(uint4v* d0, uint4v* d1, const void* p) {
  asm volatile("global_load_dwordx4 %0, %2, off sc0 sc1\n\t"
               "global_load_dwordx4 %1, %2, off offset:16 sc0 sc1"
               : "=&v"(*d0), "=&v"(*d1) : "v"((u64)p) : "memory");
}

// ---------- cast fp32 -> bf16(raw u16) ----------
__global__ void cast_f32_bf16(const float* __restrict__ src, unsigned short* __restrict__ dst, int n) {
  int i = blockIdx.x * blockDim.x + threadIdx.x;
  int stride = gridDim.x * blockDim.x;
  for (; i < n; i += stride) dst[i] = f2bf(src[i]);
}

// prefill tagged h0: tag=0 in high16, bf16(h0) in low16
__global__ void prefill_h0(const float* __restrict__ h0, u32* __restrict__ hxB, int n) {
  int i = blockIdx.x * blockDim.x + threadIdx.x;
  if (i < n) hxB[i] = (u32)f2bf(h0[i]);
}

// ---------- GEMM: C_bf[M,N] = act(A_bf[M,K] @ W_bf[N,K]^T + bias[N]) ----------
template<bool RELU>
__global__ __launch_bounds__(256)
void gemm_bt(const unsigned short* __restrict__ A, const unsigned short* __restrict__ W,
             const float* __restrict__ bias, unsigned short* __restrict__ C,
             int N, int K) {
  __shared__ unsigned short sA[128 * 64];
  __shared__ unsigned short sB[128 * 64];
  const int tid = threadIdx.x;
  const int w = tid >> 6, lane = tid & 63;
  const int l15 = lane & 15, l4 = lane >> 4;
  const int nbn = N >> 7;
  const int bm = blockIdx.x / nbn, bn = blockIdx.x % nbn;

  f32x4 acc[4][4];
  const f32x4 fz = {0.f, 0.f, 0.f, 0.f};
#pragma unroll
  for (int i = 0; i < 4; i++)
#pragma unroll
    for (int j = 0; j < 4; j++) acc[i][j] = fz;

  const int nk = K >> 6;
  for (int bk = 0; bk < nk; ++bk) {
#pragma unroll
    for (int it = 0; it < 4; ++it) {
      int slot = it * 256 + tid;
      int row = slot >> 3, c16 = slot & 7;
      const unsigned short* ga = A + (size_t)(bm * 128 + row) * K + bk * 64 + c16 * 8;
      const unsigned short* gb = W + (size_t)(bn * 128 + row) * K + bk * 64 + c16 * 8;
      unsigned ldsoff = (unsigned)(it * 256 + w * 64) * 16;
      gload_lds16(ga, sA, ldsoff);
      gload_lds16(gb, sB, ldsoff);
    }
    __syncthreads();
#pragma unroll
    for (int kt = 0; kt < 2; ++kt) {
      bf16x8 af[4], bfr[4];
#pragma unroll
      for (int m = 0; m < 4; m++) {
        int row = ((w >> 1) * 64) + m * 16 + l15;
        af[m] = ld_bf8_g(&sA[row * 64 + kt * 32 + l4 * 8]);
      }
#pragma unroll
      for (int n = 0; n < 4; n++) {
        int row = ((w & 1) * 64) + n * 16 + l15;
        bfr[n] = ld_bf8_g(&sB[row * 64 + kt * 32 + l4 * 8]);
      }
#pragma unroll
      for (int m = 0; m < 4; m++)
#pragma unroll
        for (int n = 0; n < 4; n++)
          acc[m][n] = __builtin_amdgcn_mfma_f32_16x16x32_bf16(af[m], bfr[n], acc[m][n], 0, 0, 0);
    }
    __syncthreads();
  }

  const int r0 = bm * 128 + (w >> 1) * 64;
  const int c0 = bn * 128 + (w & 1) * 64;
#pragma unroll
  for (int n = 0; n < 4; n++) {
    int c = c0 + n * 16 + l15;
    float b = bias[c];
#pragma unroll
    for (int m = 0; m < 4; m++)
#pragma unroll
      for (int j = 0; j < 4; j++) {
        int r = r0 + m * 16 + l4 * 4 + j;
        float v = acc[m][n][j] + b;
        if (RELU) v = fmaxf(v, 0.f);
        C[(size_t)r * N + c] = f2bf(v);
      }
  }
}

// ---------- persistent GRU scan: per-word VERSION-TAGGED exchange ----------
// 128 WGs = 8 seq-groups(32 seqs) x 16 col-WGs(32 cols); 256 threads = 4 waves.
// Wave (mm,e): rows mm*16..+16, cols e*16..+16, all 3 gates, full K=512.
// Exchange word: u32 = (tag:16 <<16) | bf16(h).  tag = t+1 for h_t.
// PRODUCER: 4 relaxed-agent u32 stores, fire-and-forget. NO drain, NO flag,
//   NO publish phase — each word is self-certifying (u32 single-copy atomic).
// CONSUMER: loads its 16 A-chunks (sc0 sc1, bypass L1/L2), checks tags in-reg,
//   re-loads only stale chunks with s_sleep(2) backoff. Detect+read = ONE trip.
// WAR: producer overwrites tag-t slots (parity) only at step t+2, after acquiring
//   tag-(t+1) data from every same-mm wave => all readers of tag-t finished.
// Cross-replay: hxA memset 0xFF (tag 0xffff never valid), hxB re-prefilled (tag 0).
#define GRU_LDS_BYTES (96 * 1024)

__global__ __launch_bounds__(256, 1)
void gru_scan(const unsigned short* __restrict__ whh,
              const float* __restrict__ b_hh,
              const unsigned short* __restrict__ gi,
              const float* __restrict__ h0f,
              u32* __restrict__ hxA,              // parity 0 writes (memset 0xFF)
              u32* __restrict__ hxB,              // parity 1 writes (prefilled tag0|h0)
              float* __restrict__ hout) {
  extern __shared__ char lds[];
  unsigned short* sW = (unsigned short*)lds;      // [96][512] bf16, swizzled

  const int tid = threadIdx.x;
  const int w = tid >> 6, lane = tid & 63, l15 = lane & 15, l4 = lane >> 4;
  const int sg = blockIdx.x >> 4, cg = blockIdx.x & 15;
  const int s0 = sg * 32;
  const int c0 = cg * 32;
  const int mm = w >> 1, e = w & 1;

  // ---- one-time: stage whh slice rows (gate*512 + c0 + 0..31) ----
  for (int it = 0; it < 24; ++it) {
    int slot = it * 256 + tid;                 // 6144 slots of 16B
    int lcr = slot >> 6, c16 = slot & 63;      // lcr 0..95
    int grow = (lcr >> 5) * 512 + c0 + (lcr & 31);
    ushort8 v = *(const ushort8*)(whh + (size_t)grow * 512 + c16 * 8);
    unsigned byte = ((unsigned)(lcr * 1024 + c16 * 16)) ^ ((unsigned)(lcr & 7) << 4);
    *(ushort8*)((char*)sW + byte) = v;
  }

  // ---- per-thread constants ----
  const int c = c0 + e * 16 + l15;             // output col
  int rj[4];
#pragma unroll
  for (int j = 0; j < 4; ++j) rj[j] = s0 + mm * 16 + l4 * 4 + j;
  float bias0 = b_hh[c], bias1 = b_hh[512 + c], bias2 = b_hh[1024 + c];
  float hp[4];
#pragma unroll
  for (int j = 0; j < 4; ++j) hp[j] = h0f[(size_t)rj[j] * HH + c];
  size_t houtb[4], gib[4];
#pragma unroll
  for (int j = 0; j < 4; ++j) {
    houtb[j] = (size_t)rj[j] * TT * HH + c;
    gib[j]   = (size_t)rj[j] * TT * G3 + c;
  }
  const int arow = s0 + mm * 16 + l15;         // A-fragment row for this lane

  // ---- prologue: gi(0) loads (retire during staging) ----
  unsigned short gnext[12];
#pragma unroll
  for (int j = 0; j < 4; ++j) {
    const unsigned short* gp = gi + gib[j];
    gnext[j * 3 + 0] = gp[0];
    gnext[j * 3 + 1] = gp[512];
    gnext[j * 3 + 2] = gp[1024];
  }

  __syncthreads();  // sW ready (only barrier in the kernel)

#pragma unroll 1
  for (int t = 0; t < TT; ++t) {
    const u32* rx = (t & 1) ? hxA : hxB;       // holds tag-t data
    u32* wx = (t & 1) ? hxB : hxA;             // receives tag-(t+1) data

    // convert gi(t) (loaded during previous step; long retired)
    float gv0[4], gv1[4], gv2[4];
#pragma unroll
    for (int j = 0; j < 4; ++j) {
      gv0[j] = bf2f(gnext[j * 3 + 0]);
      gv1[j] = bf2f(gnext[j * 3 + 1]);
      gv2[j] = bf2f(gnext[j * 3 + 2]);
    }

    // ---- ACQUIRE: load all 16 chunks, verify tags, retry only stale ----
    const u32* abase = rx + (size_t)arow * 512 + l4 * 8;
    uint4v q0[16], q1[16];
    const u32 texp = (u32)t << 16;
    u32 stale = 0xffffu;
    do {
#pragma unroll
      for (int i = 0; i < 16; ++i)
        if ((stale >> i) & 1u)
          ld32_sc(&q0[i], &q1[i], abase + i * 32);
      asm volatile("s_waitcnt vmcnt(0)" ::: "memory");
      u32 ns = 0;
#pragma unroll
      for (int i = 0; i < 16; ++i) {
        if ((stale >> i) & 1u) {
          u32 acc = (q0[i][0] ^ texp) | (q0[i][1] ^ texp) | (q0[i][2] ^ texp) | (q0[i][3] ^ texp)
                  | (q1[i][0] ^ texp) | (q1[i][1] ^ texp) | (q1[i][2] ^ texp) | (q1[i][3] ^ texp);
          bool ok = (acc & 0xffff0000u) == 0u;
          if (__ballot(ok) != ~0ull) ns |= 1u << i;
        }
      }
      if (ns) __builtin_amdgcn_s_sleep(2);
      stale = ns;
    } while (stale);
    __builtin_amdgcn_sched_barrier(0);

    // ---- issue gi(t+1): retires under the MFMA phase ----
    {
      int tn = (t + 1 < TT) ? t + 1 : t;
#pragma unroll
      for (int j = 0; j < 4; ++j) {
        const unsigned short* gp = gi + gib[j] + (size_t)tn * G3;
        gnext[j * 3 + 0] = gp[0];
        gnext[j * 3 + 1] = gp[512];
        gnext[j * 3 + 2] = gp[1024];
      }
    }

    // ---- unpack (v_perm pairs) + MFMA: 16 chunks x 3 gates ----
    f32x4 acc[3];
    const f32x4 fz = {0.f, 0.f, 0.f, 0.f};
    acc[0] = fz; acc[1] = fz; acc[2] = fz;
#pragma unroll
    for (int i = 0; i < 16; ++i) {
      u32 w0 = __builtin_amdgcn_perm(q0[i][1], q0[i][0], 0x05040100u);
      u32 w1 = __builtin_amdgcn_perm(q0[i][3], q0[i][2], 0x05040100u);
      u32 w2 = __builtin_amdgcn_perm(q1[i][1], q1[i][0], 0x05040100u);
      u32 w3 = __builtin_amdgcn_perm(q1[i][3], q1[i][2], 0x05040100u);
      uint4v aw = {w0, w1, w2, w3};
      bf16x8 a = __builtin_bit_cast(bf16x8, aw);
#pragma unroll
      for (int g = 0; g < 3; ++g) {
        int lcr = g * 32 + e * 16 + l15;
        unsigned byte = ((unsigned)(lcr * 1024 + i * 64 + l4 * 16)) ^ ((unsigned)(lcr & 7) << 4);
        bf16x8 b = ld_bf8_b((const char*)sW, byte);
        acc[g] = __builtin_amdgcn_mfma_f32_16x16x32_bf16(a, b, acc[g], 0, 0, 0);
      }
    }

    // ---- epilogue ----
    float hn[4];
#pragma unroll
    for (int j = 0; j < 4; ++j) {
      float gh0 = acc[0][j] + bias0;
      float gh1 = acc[1][j] + bias1;
      float gh2 = acc[2][j] + bias2;
      float rr = 1.f / (1.f + __expf(-(gv0[j] + gh0)));
      float zz = 1.f / (1.f + __expf(-(gv1[j] + gh1)));
      float nx = gv2[j] + rr * gh2;
      float ex = __expf(2.f * nx);
      float nn = 1.f - 2.f / (ex + 1.f);       // tanh, inf-safe
      hn[j] = (1.f - zz) * nn + zz * hp[j];
      hp[j] = hn[j];
    }

    // ---- exchange: tagged u32 stores, fire-and-forget (NO drain, NO flag) ----
    {
      const u32 tagw = ((u32)(t + 1)) << 16;
#pragma unroll
      for (int j = 0; j < 4; ++j) {
        u32 word = tagw | (u32)f2bf(hn[j]);
        __hip_atomic_store(wx + (size_t)rj[j] * 512 + c, word,
                           __ATOMIC_RELAXED, __HIP_MEMORY_SCOPE_AGENT);
      }
    }

    // ---- hout: plain cached stores (flushed at kernel end) ----
#pragma unroll
    for (int j = 0; j < 4; ++j)
      hout[houtb[j] + (size_t)t * HH] = hn[j];
  }
}

// ---------- decoder + softmax ----------
__global__ __launch_bounds__(256)
void decoder_softmax(const float* __restrict__ hf,
                     const unsigned short* __restrict__ dwb,
                     const float* __restrict__ dec_b,
                     float* __restrict__ pi) {
  __shared__ unsigned short sH[64 * 512];
  const int tid = threadIdx.x, w = tid >> 6, lane = tid & 63, l15 = lane & 15, l4 = lane >> 4;
  const size_t m0 = (size_t)blockIdx.x * 64;

#pragma unroll
  for (int it = 0; it < 16; ++it) {
    int slot = it * 256 + tid;
    int row = slot >> 6, c16 = slot & 63;
    const float* g = hf + (m0 + row) * 512 + c16 * 8;
    float4v v0 = *(const float4v*)g;
    float4v v1 = *(const float4v*)(g + 4);
    ushort8 u;
    u[0] = f2bf(v0[0]); u[1] = f2bf(v0[1]); u[2] = f2bf(v0[2]); u[3] = f2bf(v0[3]);
    u[4] = f2bf(v1[0]); u[5] = f2bf(v1[1]); u[6] = f2bf(v1[2]); u[7] = f2bf(v1[3]);
    unsigned byte = ((unsigned)(row * 1024 + c16 * 16)) ^ ((unsigned)(row & 7) << 4);
    *(ushort8*)((char*)sH + byte) = u;
  }
  __syncthreads();

  f32x4 acc[4];
  const f32x4 fz = {0.f, 0.f, 0.f, 0.f};
#pragma unroll
  for (int n = 0; n < 4; n++) acc[n] = fz;

  for (int kt = 0; kt < 16; ++kt) {
    int row = w * 16 + l15;
    unsigned byte = ((unsigned)(row * 1024 + kt * 64 + l4 * 16)) ^ ((unsigned)(row & 7) << 4);
    bf16x8 a = ld_bf8_b((const char*)sH, byte);
#pragma unroll
    for (int nt = 0; nt < 4; nt++) {
      bf16x8 b = ld_bf8_g(dwb + (size_t)(nt * 16 + l15) * 512 + kt * 32 + l4 * 8);
      acc[nt] = __builtin_amdgcn_mfma_f32_16x16x32_bf16(a, b, acc[nt], 0, 0, 0);
    }
  }

#pragma unroll
  for (int j = 0; j < 4; j++) {
    size_t r = m0 + w * 16 + l4 * 4 + j;
    float v[4];
    float mx = -1e30f;
#pragma unroll
    for (int nt = 0; nt < 4; nt++) {
      v[nt] = fmaxf(acc[nt][j] + dec_b[nt * 16 + l15], 0.f);
      mx = fmaxf(mx, v[nt]);
    }
#pragma unroll
    for (int msk = 1; msk <= 8; msk <<= 1) mx = fmaxf(mx, __shfl_xor(mx, msk));
    float s = 0.f;
#pragma unroll
    for (int nt = 0; nt < 4; nt++) { v[nt] = __expf(v[nt] - mx); s += v[nt]; }
#pragma unroll
    for (int msk = 1; msk <= 8; msk <<= 1) s += __shfl_xor(s, msk);
    float inv = 1.f / s;
#pragma unroll
    for (int nt = 0; nt < 4; nt++) pi[r * 64 + nt * 16 + l15] = v[nt] * inv;
  }
}

extern "C" void kernel_launch(void* const* d_in, const int* in_sizes, int n_in,
                              void* d_out, int out_size, void* d_ws, size_t ws_size,
                              hipStream_t stream) {
  const float* x     = (const float*)d_in[0];
  const float* h0    = (const float*)d_in[1];
  const float* enc_w = (const float*)d_in[2];
  const float* enc_b = (const float*)d_in[3];
  const float* w_ih  = (const float*)d_in[4];
  const float* w_hh  = (const float*)d_in[5];
  const float* b_ih  = (const float*)d_in[6];
  const float* b_hh  = (const float*)d_in[7];
  const float* dec_w = (const float*)d_in[8];
  const float* dec_b = (const float*)d_in[9];

  float* pi_out = (float*)d_out;
  float* h_out  = (float*)d_out + 4194304;

  unsigned short* ws = (unsigned short*)d_ws;
  size_t off = 0;
  unsigned short* x_bf    = ws + off; off += (size_t)MROWS * VV;
  unsigned short* enc_bf  = ws + off; off += (size_t)MROWS * EE;
  unsigned short* gi_bf   = ws + off; off += (size_t)MROWS * G3;
  unsigned short* encw_bf = ws + off; off += (size_t)EE * VV;
  unsigned short* wih_bf  = ws + off; off += (size_t)G3 * EE;
  unsigned short* whh_bf  = ws + off; off += (size_t)G3 * HH;
  unsigned short* decw_bf = ws + off; off += (size_t)NA * HH;
  u32* hxA = (u32*)(ws + off); off += (size_t)NSEQ * HH * 2;   // 131072 u32
  u32* hxB = (u32*)(ws + off); off += (size_t)NSEQ * HH * 2;   // 131072 u32
  (void)ws_size; (void)in_sizes; (void)n_in; (void)out_size;

  hipFuncSetAttribute((const void*)gru_scan,
                      hipFuncAttributeMaxDynamicSharedMemorySize, GRU_LDS_BYTES);

  auto cast = [&](const float* s, unsigned short* d, int n) {
    int blocks = (n + 255) / 256; if (blocks > 2048) blocks = 2048;
    cast_f32_bf16<<<blocks, 256, 0, stream>>>(s, d, n);
  };
  cast(x, x_bf, MROWS * VV);
  cast(enc_w, encw_bf, EE * VV);
  cast(w_ih, wih_bf, G3 * EE);
  cast(w_hh, whh_bf, G3 * HH);
  cast(dec_w, decw_bf, NA * HH);

  // tagged exchange buffers: A = invalid tag 0xffff; B = tag0 | bf16(h0)
  hipMemsetAsync(hxA, 0xFF, (size_t)NSEQ * HH * 4, stream);
  prefill_h0<<<(NSEQ * HH) / 256, 256, 0, stream>>>(h0, hxB, NSEQ * HH);

  gemm_bt<true><<<(MROWS / 128) * (EE / 128), 256, 0, stream>>>(x_bf, encw_bf, enc_b, enc_bf, EE, VV);
  gemm_bt<false><<<(MROWS / 128) * (G3 / 128), 256, 0, stream>>>(enc_bf, wih_bf, b_ih, gi_bf, G3, EE);

  gru_scan<<<dim3(128), dim3(256), GRU_LDS_BYTES, stream>>>(
      whh_bf, b_hh, gi_bf, h0, hxA, hxB, h_out);

  decoder_softmax<<<1024, 256, 0, stream>>>(h_out, decw_bf, dec_b, pi_out);
}

// Round 12
// 1718.334 us; speedup vs baseline: 1.1918x; 1.1918x over previous
//
#include <hip/hip_runtime.h>
#include <hip/hip_bf16.h>

typedef __bf16 bf16x8 __attribute__((ext_vector_type(8)));
typedef float f32x4 __attribute__((ext_vector_type(4)));
typedef unsigned short ushort8 __attribute__((ext_vector_type(8)));
typedef float float4v __attribute__((ext_vector_type(4)));
typedef unsigned int uint4v __attribute__((ext_vector_type(4)));
typedef unsigned long long u64;
typedef unsigned int u32;

#define DEVI __device__ __forceinline__

// ---- sizes (compile-time) ----
#define NSEQ 256      // A_*BS
#define TT 256        // T
#define VV 128        // V
#define EE 512        // E
#define HH 512        // H
#define NA 64
#define MROWS 65536   // NSEQ*T
#define G3 1536       // 3*H

DEVI unsigned short f2bf(float f) {
  union { float f; unsigned u; } v; v.f = f;
  unsigned r = v.u + 0x7fffu + ((v.u >> 16) & 1u);
  return (unsigned short)(r >> 16);
}
DEVI float bf2f(unsigned short s) {
  union { unsigned u; float f; } v; v.u = ((unsigned)s) << 16;
  return v.f;
}
DEVI bf16x8 ld_bf8_g(const unsigned short* p) {
  ushort8 v = *(const ushort8*)p;
  return __builtin_bit_cast(bf16x8, v);
}
DEVI bf16x8 ld_bf8_b(const char* base, unsigned byte) {
  ushort8 v = *(const ushort8*)(base + byte);
  return __builtin_bit_cast(bf16x8, v);
}
DEVI void gload_lds16(const void* g, unsigned short* lds_base, unsigned lds_byte_off) {
  __builtin_amdgcn_global_load_lds(
      (const __attribute__((address_space(1))) unsigned int*)g,
      (__attribute__((address_space(3))) unsigned int*)(void*)((char*)lds_base + lds_byte_off),
      16, 0, 0);
}
// LLC-coherent 16B load (bypass L1+L2). Issue only; caller waits vmcnt.
DEVI void ld_chunk_sc(uint4v* dst, const void* p) {
  asm volatile("global_load_dwordx4 %0, %1, off sc0 sc1"
               : "=&v"(*dst) : "v"((u64)p) : "memory");
}

// ---------- cast fp32 -> bf16(raw u16) ----------
__global__ void cast_f32_bf16(const float* __restrict__ src, unsigned short* __restrict__ dst, int n) {
  int i = blockIdx.x * blockDim.x + threadIdx.x;
  int stride = gridDim.x * blockDim.x;
  for (; i < n; i += stride) dst[i] = f2bf(src[i]);
}

__global__ void zero_u32(u32* __restrict__ p, int n) {
  int i = blockIdx.x * blockDim.x + threadIdx.x;
  if (i < n) p[i] = 0u;
}

// ---------- GEMM: C_bf[M,N] = act(A_bf[M,K] @ W_bf[N,K]^T + bias[N]) ----------
template<bool RELU>
__global__ __launch_bounds__(256)
void gemm_bt(const unsigned short* __restrict__ A, const unsigned short* __restrict__ W,
             const float* __restrict__ bias, unsigned short* __restrict__ C,
             int N, int K) {
  __shared__ unsigned short sA[128 * 64];
  __shared__ unsigned short sB[128 * 64];
  const int tid = threadIdx.x;
  const int w = tid >> 6, lane = tid & 63;
  const int l15 = lane & 15, l4 = lane >> 4;
  const int nbn = N >> 7;
  const int bm = blockIdx.x / nbn, bn = blockIdx.x % nbn;

  f32x4 acc[4][4];
  const f32x4 fz = {0.f, 0.f, 0.f, 0.f};
#pragma unroll
  for (int i = 0; i < 4; i++)
#pragma unroll
    for (int j = 0; j < 4; j++) acc[i][j] = fz;

  const int nk = K >> 6;
  for (int bk = 0; bk < nk; ++bk) {
#pragma unroll
    for (int it = 0; it < 4; ++it) {
      int slot = it * 256 + tid;
      int row = slot >> 3, c16 = slot & 7;
      const unsigned short* ga = A + (size_t)(bm * 128 + row) * K + bk * 64 + c16 * 8;
      const unsigned short* gb = W + (size_t)(bn * 128 + row) * K + bk * 64 + c16 * 8;
      unsigned ldsoff = (unsigned)(it * 256 + w * 64) * 16;
      gload_lds16(ga, sA, ldsoff);
      gload_lds16(gb, sB, ldsoff);
    }
    __syncthreads();
#pragma unroll
    for (int kt = 0; kt < 2; ++kt) {
      bf16x8 af[4], bfr[4];
#pragma unroll
      for (int m = 0; m < 4; m++) {
        int row = ((w >> 1) * 64) + m * 16 + l15;
        af[m] = ld_bf8_g(&sA[row * 64 + kt * 32 + l4 * 8]);
      }
#pragma unroll
      for (int n = 0; n < 4; n++) {
        int row = ((w & 1) * 64) + n * 16 + l15;
        bfr[n] = ld_bf8_g(&sB[row * 64 + kt * 32 + l4 * 8]);
      }
#pragma unroll
      for (int m = 0; m < 4; m++)
#pragma unroll
        for (int n = 0; n < 4; n++)
          acc[m][n] = __builtin_amdgcn_mfma_f32_16x16x32_bf16(af[m], bfr[n], acc[m][n], 0, 0, 0);
    }
    __syncthreads();
  }

  const int r0 = bm * 128 + (w >> 1) * 64;
  const int c0 = bn * 128 + (w & 1) * 64;
#pragma unroll
  for (int n = 0; n < 4; n++) {
    int c = c0 + n * 16 + l15;
    float b = bias[c];
#pragma unroll
    for (int m = 0; m < 4; m++)
#pragma unroll
      for (int j = 0; j < 4; j++) {
        int r = r0 + m * 16 + l4 * 4 + j;
        float v = acc[m][n][j] + b;
        if (RELU) v = fmaxf(v, 0.f);
        C[(size_t)r * N + c] = f2bf(v);
      }
  }
}

// ---------- persistent GRU scan (R9 structure + register hout ring) ----------
// 128 WGs = 8 seq-groups(32 seqs) x 16 col-WGs(32 cols); 256 threads = 4 waves.
// Wave (mm,e): rows mm*16..+16, cols e*16..+16, all 3 gates, full K=512.
// ACQUIRE: per-wave poll of the 16-WG-flag 64B line (ballot -> ready mask); chunk
//   loads issued in rotated order as producers show ready (overlap wait & pull).
// PUBLISH: per wave {exchange -> vmcnt(0) -> LDS token}; wave0 gathers -> 1 WG flag.
// hout: 4-step REGISTER ring (static tt index), bulk plain stores per block —
//   no LDS traffic, store ACKs amortized off the per-step chain.
#define GRU_LDS_BYTES (96 * 1024 + 64)

__global__ __launch_bounds__(256, 1)
void gru_scan(const unsigned short* __restrict__ whh,
              const float* __restrict__ b_hh,
              const unsigned short* __restrict__ gi,
              const float* __restrict__ h0f,
              unsigned short* __restrict__ hbA,   // parity 0 writes
              unsigned short* __restrict__ hbB,   // parity 1 writes (pre-filled f2bf(h0))
              float* __restrict__ hout,
              u32* __restrict__ flags) {          // [8 sg][32] u32 (16 used), zeroed
  extern __shared__ char lds[];
  unsigned short* sW = (unsigned short*)lds;       // [96][512] bf16, swizzled
  u32* sCtl = (u32*)(lds + 96 * 1024);             // [0..3] wave tokens

  const int tid = threadIdx.x;
  const int w = tid >> 6, lane = tid & 63, l15 = lane & 15, l4 = lane >> 4;
  const int sg = blockIdx.x >> 4, cg = blockIdx.x & 15;
  const int s0 = sg * 32;
  const int c0 = cg * 32;
  const int mm = w >> 1, e = w & 1;

  // ---- one-time: stage whh slice rows (gate*512 + c0 + 0..31) ----
  for (int it = 0; it < 24; ++it) {
    int slot = it * 256 + tid;                 // 6144 slots of 16B
    int lcr = slot >> 6, c16 = slot & 63;      // lcr 0..95
    int grow = (lcr >> 5) * 512 + c0 + (lcr & 31);
    ushort8 v = *(const ushort8*)(whh + (size_t)grow * 512 + c16 * 8);
    unsigned byte = ((unsigned)(lcr * 1024 + c16 * 16)) ^ ((unsigned)(lcr & 7) << 4);
    *(ushort8*)((char*)sW + byte) = v;
  }
  if (tid < 4) sCtl[tid] = 0;

  // ---- per-thread constants ----
  const int c = c0 + e * 16 + l15;             // output col
  int rj[4];
#pragma unroll
  for (int j = 0; j < 4; ++j) rj[j] = s0 + mm * 16 + l4 * 4 + j;
  float bias0 = b_hh[c], bias1 = b_hh[512 + c], bias2 = b_hh[1024 + c];
  float hp[4];
#pragma unroll
  for (int j = 0; j < 4; ++j) hp[j] = h0f[(size_t)rj[j] * HH + c];
  size_t houtb[4], gib[4];
#pragma unroll
  for (int j = 0; j < 4; ++j) {
    houtb[j] = (size_t)rj[j] * TT * HH + c;
    gib[j]   = (size_t)rj[j] * TT * G3 + c;
  }
  const int arow = s0 + mm * 16 + l15;         // A-fragment row for this lane
  const unsigned storej = (l15 & 1);           // even lanes store j=0,1; odd j=2,3

  u32* myflag = flags + sg * 32 + cg;          // per-WG flag
  const u32* pollp = flags + sg * 32 + l15;    // 16-flag 64B line, lane-indexed

  // ---- prologue: gi(0) loads (retire during staging) ----
  unsigned short gnext[12];
#pragma unroll
  for (int j = 0; j < 4; ++j) {
    const unsigned short* gp = gi + gib[j];
    gnext[j * 3 + 0] = gp[0];
    gnext[j * 3 + 1] = gp[512];
    gnext[j * 3 + 2] = gp[1024];
  }

  __syncthreads();  // sW + sCtl ready (only barrier in the kernel)

  float hreg[4][4];  // 4-step register hout ring (tt statically indexed)

#pragma unroll 1
  for (int tb = 0; tb < TT / 4; ++tb) {
#pragma unroll
    for (int tt = 0; tt < 4; ++tt) {
      const int t = tb * 4 + tt;
      const unsigned short* rb = (t & 1) ? hbA : hbB;
      unsigned short* wb = (t & 1) ? hbB : hbA;

      // convert gi(t) (loaded during previous step's MFMA phase; long retired)
      float gv0[4], gv1[4], gv2[4];
#pragma unroll
      for (int j = 0; j < 4; ++j) {
        gv0[j] = bf2f(gnext[j * 3 + 0]);
        gv1[j] = bf2f(gnext[j * 3 + 1]);
        gv2[j] = bf2f(gnext[j * 3 + 2]);
      }

      // ---- ACQUIRE: poll ready-mask, issue chunk loads in rotated order ----
      const char* abase = (const char*)(rb + (size_t)arow * HH) + l4 * 16;
      uint4v av4[16];
      u32 mask;
      {
        u32 fv = __hip_atomic_load(pollp, __ATOMIC_RELAXED, __HIP_MEMORY_SCOPE_AGENT);
        u64 bal = __ballot(fv >= (u32)t);
        mask = (u32)(bal & 0xffffu);
      }
#pragma unroll
      for (int i = 0; i < 16; ++i) {
        int ktg = (cg + i) & 15;
        while (!((mask >> ktg) & 1u)) {
          __builtin_amdgcn_s_sleep(1);
          u32 fv = __hip_atomic_load(pollp, __ATOMIC_RELAXED, __HIP_MEMORY_SCOPE_AGENT);
          u64 bal = __ballot(fv >= (u32)t);
          mask = (u32)(bal & 0xffffu);
        }
        ld_chunk_sc(&av4[i], abase + (size_t)ktg * 64);
      }
      asm volatile("s_waitcnt vmcnt(0)" ::: "memory");
      __builtin_amdgcn_sched_barrier(0);

      // ---- issue gi(t+1): retires under the MFMA phase ----
      {
        int tn = (t + 1 < TT) ? t + 1 : t;
#pragma unroll
        for (int j = 0; j < 4; ++j) {
          const unsigned short* gp = gi + gib[j] + (size_t)tn * G3;
          gnext[j * 3 + 0] = gp[0];
          gnext[j * 3 + 1] = gp[512];
          gnext[j * 3 + 2] = gp[1024];
        }
      }

      // ---- MFMA: 16 chunks x 3 gates ----
      f32x4 acc[3];
      const f32x4 fz = {0.f, 0.f, 0.f, 0.f};
      acc[0] = fz; acc[1] = fz; acc[2] = fz;
#pragma unroll
      for (int i = 0; i < 16; ++i) {
        int ktg = (cg + i) & 15;
        bf16x8 a = __builtin_bit_cast(bf16x8, av4[i]);
#pragma unroll
        for (int g = 0; g < 3; ++g) {
          int lcr = g * 32 + e * 16 + l15;
          unsigned byte = ((unsigned)(lcr * 1024 + ktg * 64 + l4 * 16)) ^ ((unsigned)(lcr & 7) << 4);
          bf16x8 b = ld_bf8_b((const char*)sW, byte);
          acc[g] = __builtin_amdgcn_mfma_f32_16x16x32_bf16(a, b, acc[g], 0, 0, 0);
        }
      }

      // ---- epilogue ----
      float hn[4];
#pragma unroll
      for (int j = 0; j < 4; ++j) {
        float gh0 = acc[0][j] + bias0;
        float gh1 = acc[1][j] + bias1;
        float gh2 = acc[2][j] + bias2;
        float rr = 1.f / (1.f + __expf(-(gv0[j] + gh0)));
        float zz = 1.f / (1.f + __expf(-(gv1[j] + gh1)));
        float nx = gv2[j] + rr * gh2;
        float ex = __expf(2.f * nx);
        float nn = 1.f - 2.f / (ex + 1.f);       // tanh, inf-safe
        hn[j] = (1.f - zz) * nn + zz * hp[j];
        hp[j] = hn[j];
        hreg[tt][j] = hn[j];                     // static tt index -> stays in VGPRs
      }

      // ---- exchange: pack col-pairs, relaxed u32 agent stores ----
#pragma unroll
      for (int j = 0; j < 4; ++j) {
        u32 my = f2bf(hn[j]);
        u32 oth = (u32)__shfl_xor((int)my, 1);
        u32 word = (l15 & 1) ? ((oth & 0xffffu) | (my << 16))
                             : ((my & 0xffffu) | (oth << 16));
        if ((unsigned)(j >> 1) == storej) {
          u32* dst = (u32*)(wb + (size_t)rj[j] * HH + (c & ~1));
          __hip_atomic_store(dst, word, __ATOMIC_RELAXED, __HIP_MEMORY_SCOPE_AGENT);
        }
      }

      // ---- publish: per-wave drain -> LDS token; wave0 gathers -> ONE WG flag ----
      asm volatile("s_waitcnt vmcnt(0)" ::: "memory");
      __hip_atomic_store(&sCtl[w], (u32)(t + 1), __ATOMIC_RELAXED, __HIP_MEMORY_SCOPE_WORKGROUP);
      if (w == 0) {
        u32 mt;
        do {
          u32 tv = __hip_atomic_load(&sCtl[lane & 3], __ATOMIC_RELAXED, __HIP_MEMORY_SCOPE_WORKGROUP);
          mt = tv;
#pragma unroll
          for (int msk = 1; msk <= 2; msk <<= 1) {
            u32 o = (u32)__shfl_xor((int)mt, msk);
            mt = mt < o ? mt : o;
          }
        } while (mt < (u32)(t + 1));
        if (lane == 0)
          __hip_atomic_store(myflag, (u32)(t + 1), __ATOMIC_RELAXED, __HIP_MEMORY_SCOPE_AGENT);
      }
    }

    // ---- bulk hout flush for this 4-step block (plain stores, L2 write-back) ----
#pragma unroll
    for (int tt = 0; tt < 4; ++tt)
#pragma unroll
      for (int j = 0; j < 4; ++j)
        hout[houtb[j] + (size_t)(tb * 4 + tt) * HH] = hreg[tt][j];
  }
}

// ---------- decoder + softmax ----------
__global__ __launch_bounds__(256)
void decoder_softmax(const float* __restrict__ hf,
                     const unsigned short* __restrict__ dwb,
                     const float* __restrict__ dec_b,
                     float* __restrict__ pi) {
  __shared__ unsigned short sH[64 * 512];
  const int tid = threadIdx.x, w = tid >> 6, lane = tid & 63, l15 = lane & 15, l4 = lane >> 4;
  const size_t m0 = (size_t)blockIdx.x * 64;

#pragma unroll
  for (int it = 0; it < 16; ++it) {
    int slot = it * 256 + tid;
    int row = slot >> 6, c16 = slot & 63;
    const float* g = hf + (m0 + row) * 512 + c16 * 8;
    float4v v0 = *(const float4v*)g;
    float4v v1 = *(const float4v*)(g + 4);
    ushort8 u;
    u[0] = f2bf(v0[0]); u[1] = f2bf(v0[1]); u[2] = f2bf(v0[2]); u[3] = f2bf(v0[3]);
    u[4] = f2bf(v1[0]); u[5] = f2bf(v1[1]); u[6] = f2bf(v1[2]); u[7] = f2bf(v1[3]);
    unsigned byte = ((unsigned)(row * 1024 + c16 * 16)) ^ ((unsigned)(row & 7) << 4);
    *(ushort8*)((char*)sH + byte) = u;
  }
  __syncthreads();

  f32x4 acc[4];
  const f32x4 fz = {0.f, 0.f, 0.f, 0.f};
#pragma unroll
  for (int n = 0; n < 4; n++) acc[n] = fz;

  for (int kt = 0; kt < 16; ++kt) {
    int row = w * 16 + l15;
    unsigned byte = ((unsigned)(row * 1024 + kt * 64 + l4 * 16)) ^ ((unsigned)(row & 7) << 4);
    bf16x8 a = ld_bf8_b((const char*)sH, byte);
#pragma unroll
    for (int nt = 0; nt < 4; nt++) {
      bf16x8 b = ld_bf8_g(dwb + (size_t)(nt * 16 + l15) * 512 + kt * 32 + l4 * 8);
      acc[nt] = __builtin_amdgcn_mfma_f32_16x16x32_bf16(a, b, acc[nt], 0, 0, 0);
    }
  }

#pragma unroll
  for (int j = 0; j < 4; j++) {
    size_t r = m0 + w * 16 + l4 * 4 + j;
    float v[4];
    float mx = -1e30f;
#pragma unroll
    for (int nt = 0; nt < 4; nt++) {
      v[nt] = fmaxf(acc[nt][j] + dec_b[nt * 16 + l15], 0.f);
      mx = fmaxf(mx, v[nt]);
    }
#pragma unroll
    for (int msk = 1; msk <= 8; msk <<= 1) mx = fmaxf(mx, __shfl_xor(mx, msk));
    float s = 0.f;
#pragma unroll
    for (int nt = 0; nt < 4; nt++) { v[nt] = __expf(v[nt] - mx); s += v[nt]; }
#pragma unroll
    for (int msk = 1; msk <= 8; msk <<= 1) s += __shfl_xor(s, msk);
    float inv = 1.f / s;
#pragma unroll
    for (int nt = 0; nt < 4; nt++) pi[r * 64 + nt * 16 + l15] = v[nt] * inv;
  }
}

extern "C" void kernel_launch(void* const* d_in, const int* in_sizes, int n_in,
                              void* d_out, int out_size, void* d_ws, size_t ws_size,
                              hipStream_t stream) {
  const float* x     = (const float*)d_in[0];
  const float* h0    = (const float*)d_in[1];
  const float* enc_w = (const float*)d_in[2];
  const float* enc_b = (const float*)d_in[3];
  const float* w_ih  = (const float*)d_in[4];
  const float* w_hh  = (const float*)d_in[5];
  const float* b_ih  = (const float*)d_in[6];
  const float* b_hh  = (const float*)d_in[7];
  const float* dec_w = (const float*)d_in[8];
  const float* dec_b = (const float*)d_in[9];

  float* pi_out = (float*)d_out;
  float* h_out  = (float*)d_out + 4194304;

  unsigned short* ws = (unsigned short*)d_ws;
  size_t off = 0;
  unsigned short* x_bf    = ws + off; off += (size_t)MROWS * VV;
  unsigned short* enc_bf  = ws + off; off += (size_t)MROWS * EE;
  unsigned short* gi_bf   = ws + off; off += (size_t)MROWS * G3;
  unsigned short* encw_bf = ws + off; off += (size_t)EE * VV;
  unsigned short* wih_bf  = ws + off; off += (size_t)G3 * EE;
  unsigned short* whh_bf  = ws + off; off += (size_t)G3 * HH;
  unsigned short* decw_bf = ws + off; off += (size_t)NA * HH;
  unsigned short* hb0     = ws + off; off += (size_t)NSEQ * HH;
  unsigned short* hb1     = ws + off; off += (size_t)NSEQ * HH;
  u32* flags = (u32*)((((uintptr_t)(ws + off)) + 255) & ~(uintptr_t)255);
  (void)ws_size; (void)in_sizes; (void)n_in; (void)out_size;

  hipFuncSetAttribute((const void*)gru_scan,
                      hipFuncAttributeMaxDynamicSharedMemorySize, GRU_LDS_BYTES);

  auto cast = [&](const float* s, unsigned short* d, int n) {
    int blocks = (n + 255) / 256; if (blocks > 2048) blocks = 2048;
    cast_f32_bf16<<<blocks, 256, 0, stream>>>(s, d, n);
  };
  cast(x, x_bf, MROWS * VV);
  cast(enc_w, encw_bf, EE * VV);
  cast(w_ih, wih_bf, G3 * EE);
  cast(w_hh, whh_bf, G3 * HH);
  cast(dec_w, decw_bf, NA * HH);
  cast(h0, hb1, NSEQ * HH);              // t=0 reads hbB == hb1

  zero_u32<<<1, 256, 0, stream>>>(flags, 256);

  gemm_bt<true><<<(MROWS / 128) * (EE / 128), 256, 0, stream>>>(x_bf, encw_bf, enc_b, enc_bf, EE, VV);
  gemm_bt<false><<<(MROWS / 128) * (G3 / 128), 256, 0, stream>>>(enc_bf, wih_bf, b_ih, gi_bf, G3, EE);

  gru_scan<<<dim3(128), dim3(256), GRU_LDS_BYTES, stream>>>(
      whh_bf, b_hh, gi_bf, h0, hb0, hb1, h_out, flags);

  decoder_softmax<<<1024, 256, 0, stream>>>(h_out, decw_bf, dec_b, pi_out);
}